// Round 7
// baseline (232.642 us; speedup 1.0000x reference)
//
#include <hip/hip_runtime.h>

// DynamicQuantizer: power-iteration score -> conditional rank-1 scale -> int4 fake-quant.
// X: [8192, 4096] f32. Output f32 same shape.
//
// Pipeline (3 X reads + 1 nt-write on the hot path, 6 dispatches):
//   1. memset ws (w1,w2,scal)
//   2. xtxv<0,1>: w1 += X^T (X v0)          [atomic flush; fused frob + max|X|]
//   3. xtxv<1,0>: w2 += X^T (X w1/||w1||)   [atomic flush; norm computed in-block]
//   4. quantsig: sigma^2 = ||X w2/||w2||||^2 AND out = quant(X, max|X|/7) in one X read;
//      output written with NON-TEMPORAL stores (out never re-read; avoids evicting X
//      from the 256MB L3 mid-kernel — X 128MB + out 128MB would exactly fill it)
//   5. fixup_max: early-exit if score<=0.35; else max|X_adapt| -> scal[11]
//   6. fixup_quant: early-exit if score<=0.35; else re-quant (exact flag-1 branch)
//
// R4 lesson (journal): fusing c-staging + max|X_adapt| into xtxv spilled cur[16] to
// scratch (WRITE_SIZE 40MB, 110µs). Stats kept to 2 scalar accumulators only.
// R6 lesson: __builtin_nontemporal_store needs a NATIVE vector type, not HIP float4 —
// use ext_vector_type(4) alias for the store.
//
// ws (floats): [0,4096) w1 | [4096,8192) w2 | [8192,8208) scal
//   scal: 8 sigma_sq, 9 frob, 10 max|X| bits, 11 max|X_adapt| bits

#define NR 8192
#define HC 4096
#define H4 (HC / 4)
#define EPSV 1e-8f
#define NB 512

typedef float nfloat4 __attribute__((ext_vector_type(4)));  // native vec for nt stores

__device__ __forceinline__ float wave_sum(float v) {
#pragma unroll
    for (int m = 32; m; m >>= 1) v += __shfl_xor(v, m);
    return v;
}

// Combine 4 waves' column-partials in LDS, then atomicAdd the block total into w.
__device__ __forceinline__ void flush_atomic(const float4 (&wa)[16], float4* wredA,
                                             float4* wredB, float* __restrict__ w,
                                             int t, int lane, int wid) {
    if (wid == 0) {
#pragma unroll
        for (int j = 0; j < 16; ++j) wredA[j * 64 + lane] = wa[j];
    } else if (wid == 1) {
#pragma unroll
        for (int j = 0; j < 16; ++j) wredB[j * 64 + lane] = wa[j];
    }
    __syncthreads();
    if (wid == 2) {
#pragma unroll
        for (int j = 0; j < 16; ++j) {
            float4 a = wredA[j * 64 + lane];
            a.x += wa[j].x; a.y += wa[j].y; a.z += wa[j].z; a.w += wa[j].w;
            wredA[j * 64 + lane] = a;
        }
    } else if (wid == 3) {
#pragma unroll
        for (int j = 0; j < 16; ++j) {
            float4 b = wredB[j * 64 + lane];
            b.x += wa[j].x; b.y += wa[j].y; b.z += wa[j].z; b.w += wa[j].w;
            wredB[j * 64 + lane] = b;
        }
    }
    __syncthreads();
#pragma unroll
    for (int k = 0; k < 4; ++k) {
        int idx4 = t + k * 256;
        float4 a = wredA[idx4];
        float4 b = wredB[idx4];
        a.x += b.x; a.y += b.y; a.z += b.z; a.w += b.w;
        float* wp = w + 4 * idx4;
        atomicAdd(wp + 0, a.x);
        atomicAdd(wp + 1, a.y);
        atomicAdd(wp + 2, a.z);
        atomicAdd(wp + 3, a.w);
    }
}

// Per-block partial of X^T (X v * inv) over 16 rows (4 rows/wave, row register-resident),
// accumulated straight into w via atomics.
// STATS: fuse frob + max|X| (scalar accumulators only — keeps VGPR pressure low).
// NORMIN: inv = 1/max(||v||,eps) computed in-block from staged v.
template <int NORMIN, int STATS>
__global__ __launch_bounds__(256, 1) void xtxv_kernel(
    const float4* __restrict__ X4, const float4* __restrict__ vin,
    float* __restrict__ w, float* __restrict__ scal) {
    __shared__ float4 vsh[H4];    // 16 KB staged v
    __shared__ float4 wredA[H4];  // 16 KB
    __shared__ float4 wredB[H4];  // 16 KB
    __shared__ float smn[12];
    const int t = threadIdx.x;
    const int lane = t & 63;
    const int wid = t >> 6;

    float ss = 0.f;
#pragma unroll
    for (int k = 0; k < 4; ++k) {
        int idx = t + k * 256;
        float4 vv = vin[idx];
        vsh[idx] = vv;
        if (NORMIN) ss += vv.x * vv.x + vv.y * vv.y + vv.z * vv.z + vv.w * vv.w;
    }
    if (NORMIN) {
        ss = wave_sum(ss);
        if (lane == 0) smn[wid] = ss;
    }
    __syncthreads();
    float inv = 1.0f;
    if (NORMIN) inv = 1.0f / fmaxf(sqrtf(smn[0] + smn[1] + smn[2] + smn[3]), EPSV);

    float4 wa[16];
#pragma unroll
    for (int j = 0; j < 16; ++j) wa[j] = make_float4(0.f, 0.f, 0.f, 0.f);
    const int r0 = blockIdx.x * 16 + wid * 4;
    float frob = 0.f, mx = 0.f;
    float4 cur[16];
#pragma unroll
    for (int i = 0; i < 4; ++i) {
        const float4* Xr = X4 + (size_t)(r0 + i) * H4;
#pragma unroll
        for (int j = 0; j < 16; ++j) cur[j] = Xr[lane + j * 64];
        float acc = 0.f;
#pragma unroll
        for (int j = 0; j < 16; ++j) {
            float4 x = cur[j];
            float4 vv = vsh[lane + j * 64];
            acc += x.x * vv.x + x.y * vv.y + x.z * vv.z + x.w * vv.w;
            if (STATS) {
                frob += x.x * x.x + x.y * x.y + x.z * x.z + x.w * x.w;
                mx = fmaxf(mx, fmaxf(fmaxf(fabsf(x.x), fabsf(x.y)),
                                     fmaxf(fabsf(x.z), fabsf(x.w))));
            }
        }
        acc = wave_sum(acc) * inv;
#pragma unroll
        for (int j = 0; j < 16; ++j) {
            wa[j].x += acc * cur[j].x;
            wa[j].y += acc * cur[j].y;
            wa[j].z += acc * cur[j].z;
            wa[j].w += acc * cur[j].w;
        }
    }
    if (STATS) {
#pragma unroll
        for (int m = 32; m; m >>= 1) {
            frob += __shfl_xor(frob, m);
            mx = fmaxf(mx, __shfl_xor(mx, m));
        }
        if (lane == 0) { smn[4 + wid] = frob; smn[8 + wid] = mx; }
    }
    flush_atomic(wa, wredA, wredB, w, t, lane, wid);
    if (STATS && t == 0) {
        atomicAdd(&scal[9], smn[4] + smn[5] + smn[6] + smn[7]);
        atomicMax(reinterpret_cast<unsigned*>(&scal[10]),
                  __float_as_uint(fmaxf(fmaxf(smn[8], smn[9]), fmaxf(smn[10], smn[11]))));
    }
}

// sigma^2 accumulation AND optimistic quant (flag-0 scale) in one X read.
// Output stores are non-temporal: out is never re-read, and write-allocate would evict
// X from L3 mid-kernel.
__global__ __launch_bounds__(256, 2) void quantsig_kernel(
    const float4* __restrict__ X4, const float4* __restrict__ w24,
    float* __restrict__ scal, nfloat4* __restrict__ out4) {
    __shared__ float4 vsh[H4];
    __shared__ float smn[16];
    const int t = threadIdx.x;
    const int lane = t & 63;
    const int wid = t >> 6;

    const float mv = __uint_as_float(reinterpret_cast<const unsigned*>(scal)[10]);
    const float scale0 = (mv < EPSV) ? 1.0f : mv / 7.0f;

    float ss = 0.f;
#pragma unroll
    for (int k = 0; k < 4; ++k) {
        int idx = t + k * 256;
        float4 vv = w24[idx];
        vsh[idx] = vv;
        ss += vv.x * vv.x + vv.y * vv.y + vv.z * vv.z + vv.w * vv.w;
    }
    ss = wave_sum(ss);
    if (lane == 0) smn[wid] = ss;
    __syncthreads();
    const float inv = 1.0f / fmaxf(sqrtf(smn[0] + smn[1] + smn[2] + smn[3]), EPSV);

    const int r0 = blockIdx.x * 16 + wid * 4;
    float sig = 0.f;
    float4 cur[16];
#pragma unroll
    for (int i = 0; i < 4; ++i) {
        const float4* Xr = X4 + (size_t)(r0 + i) * H4;
#pragma unroll
        for (int j = 0; j < 16; ++j) cur[j] = Xr[lane + j * 64];
        float acc = 0.f;
#pragma unroll
        for (int j = 0; j < 16; ++j) {
            float4 x = cur[j];
            float4 vv = vsh[lane + j * 64];
            acc += x.x * vv.x + x.y * vv.y + x.z * vv.z + x.w * vv.w;
        }
        acc = wave_sum(acc) * inv;
        sig += acc * acc;
        nfloat4* Or = out4 + (size_t)(r0 + i) * H4;
#pragma unroll
        for (int j = 0; j < 16; ++j) {
            float4 x = cur[j];
            nfloat4 o;
            o.x = fminf(fmaxf(rintf(x.x / scale0), -8.f), 7.f) * scale0;
            o.y = fminf(fmaxf(rintf(x.y / scale0), -8.f), 7.f) * scale0;
            o.z = fminf(fmaxf(rintf(x.z / scale0), -8.f), 7.f) * scale0;
            o.w = fminf(fmaxf(rintf(x.w / scale0), -8.f), 7.f) * scale0;
            __builtin_nontemporal_store(o, &Or[lane + j * 64]);
        }
    }
    if (lane == 0) smn[8 + wid] = sig;
    __syncthreads();
    if (t == 0) atomicAdd(&scal[8], smn[8] + smn[9] + smn[10] + smn[11]);
}

// flag==1 only: compute max|X_adapt| -> scal[11]. Early-exits otherwise.
__global__ __launch_bounds__(256) void fixup_max_kernel(
    const float4* __restrict__ X4, const float4* __restrict__ la4,
    const float4* __restrict__ lb4, float* __restrict__ scal) {
    if (!(scal[8] / (scal[9] + EPSV) > 0.35f)) return;
    __shared__ float sm[4];
    const int t = threadIdx.x;
    const int lane = t & 63;
    const int wid = t >> 6;
    float ma = 0.f;
    const size_t total4 = (size_t)NR * HC / 4;
    for (size_t i = (size_t)blockIdx.x * blockDim.x + t; i < total4;
         i += (size_t)gridDim.x * blockDim.x) {
        float4 x = X4[i];
        int h = (int)(i & (H4 - 1));
        float4 A = la4[h];
        float4 B = lb4[h];
        float ax = x.x + (x.x * (A.x * B.x)) * 0.5f;
        float ay = x.y + (x.y * (A.y * B.y)) * 0.5f;
        float az = x.z + (x.z * (A.z * B.z)) * 0.5f;
        float aw = x.w + (x.w * (A.w * B.w)) * 0.5f;
        ma = fmaxf(ma, fmaxf(fmaxf(fabsf(ax), fabsf(ay)),
                             fmaxf(fabsf(az), fabsf(aw))));
    }
#pragma unroll
    for (int m = 32; m; m >>= 1) ma = fmaxf(ma, __shfl_xor(ma, m));
    if (lane == 0) sm[wid] = ma;
    __syncthreads();
    if (t == 0)
        atomicMax(reinterpret_cast<unsigned*>(&scal[11]),
                  __float_as_uint(fmaxf(fmaxf(sm[0], sm[1]), fmaxf(sm[2], sm[3]))));
}

// flag==1 only: re-quant with adapted values (exact flag-1 branch). Early-exits otherwise.
__global__ __launch_bounds__(256) void fixup_quant_kernel(
    const float4* __restrict__ X4, const float4* __restrict__ la4,
    const float4* __restrict__ lb4, const float* __restrict__ scal,
    float4* __restrict__ out4) {
    if (!(scal[8] / (scal[9] + EPSV) > 0.35f)) return;
    const float mv = __uint_as_float(reinterpret_cast<const unsigned*>(scal)[11]);
    const float scale = (mv < EPSV) ? 1.0f : mv / 7.0f;
    const size_t total4 = (size_t)NR * HC / 4;
    for (size_t i = (size_t)blockIdx.x * blockDim.x + threadIdx.x; i < total4;
         i += (size_t)gridDim.x * blockDim.x) {
        float4 x = X4[i];
        int h = (int)(i & (H4 - 1));
        float4 A = la4[h];
        float4 B = lb4[h];
        x.x += (x.x * (A.x * B.x)) * 0.5f;
        x.y += (x.y * (A.y * B.y)) * 0.5f;
        x.z += (x.z * (A.z * B.z)) * 0.5f;
        x.w += (x.w * (A.w * B.w)) * 0.5f;
        float4 o;
        o.x = fminf(fmaxf(rintf(x.x / scale), -8.f), 7.f) * scale;
        o.y = fminf(fmaxf(rintf(x.y / scale), -8.f), 7.f) * scale;
        o.z = fminf(fmaxf(rintf(x.z / scale), -8.f), 7.f) * scale;
        o.w = fminf(fmaxf(rintf(x.w / scale), -8.f), 7.f) * scale;
        out4[i] = o;
    }
}

extern "C" void kernel_launch(void* const* d_in, const int* in_sizes, int n_in,
                              void* d_out, int out_size, void* d_ws, size_t ws_size,
                              hipStream_t stream) {
    const float4* X4 = reinterpret_cast<const float4*>(d_in[0]);
    const float4* la4 = reinterpret_cast<const float4*>(d_in[1]);
    const float4* lb4 = reinterpret_cast<const float4*>(d_in[2]);
    const float4* v04 = reinterpret_cast<const float4*>(d_in[3]);
    float* ws = (float*)d_ws;
    float* w1 = ws;
    float* w2 = ws + HC;
    float* scal = ws + 2 * HC;

    // zero w1 + w2 + scal in one memset (w1/w2 are atomic-accumulated)
    (void)hipMemsetAsync(ws, 0, (2 * HC + 16) * sizeof(float), stream);

    // power iteration 1: w1 = X^T X v0   (+ frob, max|X|)
    xtxv_kernel<0, 1><<<NB, 256, 0, stream>>>(X4, v04, w1, scal);

    // power iteration 2: w2 = X^T X (w1/||w1||)
    xtxv_kernel<1, 0><<<NB, 256, 0, stream>>>(X4, reinterpret_cast<const float4*>(w1),
                                              w2, scal);

    // sigma^2 + optimistic quant in one pass (nt stores)
    quantsig_kernel<<<NB, 256, 0, stream>>>(X4, reinterpret_cast<const float4*>(w2),
                                            scal, reinterpret_cast<nfloat4*>(d_out));

    // rare flag==1 path (both early-exit on flag==0)
    fixup_max_kernel<<<1024, 256, 0, stream>>>(X4, la4, lb4, scal);
    fixup_quant_kernel<<<1024, 256, 0, stream>>>(X4, la4, lb4, scal,
                                                 reinterpret_cast<float4*>(d_out));
}

// Round 8
// 128.329 us; speedup vs baseline: 1.8129x; 1.8129x over previous
//
#include <hip/hip_runtime.h>

// DynamicQuantizer: power-iteration score -> conditional rank-1 scale -> int4 fake-quant.
// X: [8192, 4096] f32. Output f32 same shape.
//
// Pipeline (3 X reads + 1 nt-write on the hot path, 8 dispatches):
//   1. memset ws (w1,w2,scal)
//   2. xtxv<0,1>: part = per-block X^T (X v0)    [+ fused frob + max|X|]
//   3. reduce part -> w1   (32-way atomic fan-in per column — CHEAP)
//   4. xtxv<1,0>: part = per-block X^T (X w1/||w1||)
//   5. reduce part -> w2
//   6. quantsig: sigma^2 = ||X w2/||w2||||^2 AND out = quant(X, max|X|/7) in one X read;
//      output via NON-TEMPORAL stores (out never re-read; keeps X resident in the
//      256MB L3 — X 128MB + out 128MB would exactly fill it)
//   7. fixup_max / 8. fixup_quant: early-exit unless score>0.35 (rare branch)
//
// Journal:
//  R4: fusing c-staging + max|X_adapt| into xtxv spilled cur[16] (WRITE 40MB, 110µs).
//      Stats limited to 2 scalar accumulators.
//  R7: flushing block partials with atomicAdd directly into w[4096] = 512-way
//      contention per address -> xtxv 28->127µs. Private part rows + reduce kernel win.
//  R6: __builtin_nontemporal_store needs a NATIVE vector type (ext_vector_type), not
//      HIP float4.
//
// ws (floats): [0,4096) w1 | [4096,8192) w2 | [8192,8208) scal
//   scal: 8 sigma_sq, 9 frob, 10 max|X| bits, 11 max|X_adapt| bits
// d_out doubles as the 512x4096 partial buffer until quantsig overwrites it.

#define NR 8192
#define HC 4096
#define H4 (HC / 4)
#define EPSV 1e-8f
#define NB 512

typedef float nfloat4 __attribute__((ext_vector_type(4)));  // native vec for nt stores

__device__ __forceinline__ float wave_sum(float v) {
#pragma unroll
    for (int m = 32; m; m >>= 1) v += __shfl_xor(v, m);
    return v;
}

__device__ __forceinline__ void flush_part(const float4 (&wa)[16], float4* wredA,
                                           float4* wredB, float4* dst, int t, int lane,
                                           int wid) {
    if (wid == 0) {
#pragma unroll
        for (int j = 0; j < 16; ++j) wredA[j * 64 + lane] = wa[j];
    } else if (wid == 1) {
#pragma unroll
        for (int j = 0; j < 16; ++j) wredB[j * 64 + lane] = wa[j];
    }
    __syncthreads();
    if (wid == 2) {
#pragma unroll
        for (int j = 0; j < 16; ++j) {
            float4 a = wredA[j * 64 + lane];
            a.x += wa[j].x; a.y += wa[j].y; a.z += wa[j].z; a.w += wa[j].w;
            wredA[j * 64 + lane] = a;
        }
    } else if (wid == 3) {
#pragma unroll
        for (int j = 0; j < 16; ++j) {
            float4 b = wredB[j * 64 + lane];
            b.x += wa[j].x; b.y += wa[j].y; b.z += wa[j].z; b.w += wa[j].w;
            wredB[j * 64 + lane] = b;
        }
    }
    __syncthreads();
#pragma unroll
    for (int k = 0; k < 4; ++k) {
        float4 a = wredA[t + k * 256];
        float4 b = wredB[t + k * 256];
        a.x += b.x; a.y += b.y; a.z += b.z; a.w += b.w;
        dst[t + k * 256] = a;
    }
}

// Per-block partial of X^T (X v * inv) over 16 rows (4 rows/wave, row register-resident).
// STATS: fuse frob + max|X| (scalar accumulators only — keeps VGPR pressure low).
// NORMIN: inv = 1/max(||v||,eps) computed in-block from staged v.
template <int NORMIN, int STATS>
__global__ __launch_bounds__(256, 1) void xtxv_kernel(
    const float4* __restrict__ X4, const float4* __restrict__ vin,
    float4* __restrict__ part4, float* __restrict__ scal) {
    __shared__ float4 vsh[H4];    // 16 KB staged v
    __shared__ float4 wredA[H4];  // 16 KB
    __shared__ float4 wredB[H4];  // 16 KB
    __shared__ float smn[12];
    const int t = threadIdx.x;
    const int lane = t & 63;
    const int wid = t >> 6;

    float ss = 0.f;
#pragma unroll
    for (int k = 0; k < 4; ++k) {
        int idx = t + k * 256;
        float4 vv = vin[idx];
        vsh[idx] = vv;
        if (NORMIN) ss += vv.x * vv.x + vv.y * vv.y + vv.z * vv.z + vv.w * vv.w;
    }
    if (NORMIN) {
        ss = wave_sum(ss);
        if (lane == 0) smn[wid] = ss;
    }
    __syncthreads();
    float inv = 1.0f;
    if (NORMIN) inv = 1.0f / fmaxf(sqrtf(smn[0] + smn[1] + smn[2] + smn[3]), EPSV);

    float4 wa[16];
#pragma unroll
    for (int j = 0; j < 16; ++j) wa[j] = make_float4(0.f, 0.f, 0.f, 0.f);
    const int r0 = blockIdx.x * 16 + wid * 4;
    float frob = 0.f, mx = 0.f;
    float4 cur[16];
#pragma unroll
    for (int i = 0; i < 4; ++i) {
        const float4* Xr = X4 + (size_t)(r0 + i) * H4;
#pragma unroll
        for (int j = 0; j < 16; ++j) cur[j] = Xr[lane + j * 64];
        float acc = 0.f;
#pragma unroll
        for (int j = 0; j < 16; ++j) {
            float4 x = cur[j];
            float4 vv = vsh[lane + j * 64];
            acc += x.x * vv.x + x.y * vv.y + x.z * vv.z + x.w * vv.w;
            if (STATS) {
                frob += x.x * x.x + x.y * x.y + x.z * x.z + x.w * x.w;
                mx = fmaxf(mx, fmaxf(fmaxf(fabsf(x.x), fabsf(x.y)),
                                     fmaxf(fabsf(x.z), fabsf(x.w))));
            }
        }
        acc = wave_sum(acc) * inv;
#pragma unroll
        for (int j = 0; j < 16; ++j) {
            wa[j].x += acc * cur[j].x;
            wa[j].y += acc * cur[j].y;
            wa[j].z += acc * cur[j].z;
            wa[j].w += acc * cur[j].w;
        }
    }
    if (STATS) {
#pragma unroll
        for (int m = 32; m; m >>= 1) {
            frob += __shfl_xor(frob, m);
            mx = fmaxf(mx, __shfl_xor(mx, m));
        }
        if (lane == 0) { smn[4 + wid] = frob; smn[8 + wid] = mx; }
    }
    flush_part(wa, wredA, wredB, part4 + (size_t)blockIdx.x * H4, t, lane, wid);
    if (STATS && t == 0) {
        atomicAdd(&scal[9], smn[4] + smn[5] + smn[6] + smn[7]);
        atomicMax(reinterpret_cast<unsigned*>(&scal[10]),
                  __float_as_uint(fmaxf(fmaxf(smn[8], smn[9]), fmaxf(smn[10], smn[11]))));
    }
}

// w[h] += partial column sums of part[512][HC]. 32 chunks of 16 rows per column.
__global__ __launch_bounds__(256) void reduce_part_kernel(
    const float* __restrict__ part, float* __restrict__ w) {
    const int g = blockIdx.x * 256 + threadIdx.x;  // 512 blocks -> 131072 threads
    const int h = g & (HC - 1);
    const int chunk = g >> 12;  // 0..31
    float s = 0.f;
#pragma unroll
    for (int k = 0; k < 16; ++k) s += part[(size_t)(chunk * 16 + k) * HC + h];
    atomicAdd(&w[h], s);
}

// sigma^2 accumulation AND optimistic quant (flag-0 scale) in one X read; nt stores.
__global__ __launch_bounds__(256, 2) void quantsig_kernel(
    const float4* __restrict__ X4, const float4* __restrict__ w24,
    float* __restrict__ scal, nfloat4* __restrict__ out4) {
    __shared__ float4 vsh[H4];
    __shared__ float smn[16];
    const int t = threadIdx.x;
    const int lane = t & 63;
    const int wid = t >> 6;

    const float mv = __uint_as_float(reinterpret_cast<const unsigned*>(scal)[10]);
    const float scale0 = (mv < EPSV) ? 1.0f : mv / 7.0f;

    float ss = 0.f;
#pragma unroll
    for (int k = 0; k < 4; ++k) {
        int idx = t + k * 256;
        float4 vv = w24[idx];
        vsh[idx] = vv;
        ss += vv.x * vv.x + vv.y * vv.y + vv.z * vv.z + vv.w * vv.w;
    }
    ss = wave_sum(ss);
    if (lane == 0) smn[wid] = ss;
    __syncthreads();
    const float inv = 1.0f / fmaxf(sqrtf(smn[0] + smn[1] + smn[2] + smn[3]), EPSV);

    const int r0 = blockIdx.x * 16 + wid * 4;
    float sig = 0.f;
    float4 cur[16];
#pragma unroll
    for (int i = 0; i < 4; ++i) {
        const float4* Xr = X4 + (size_t)(r0 + i) * H4;
#pragma unroll
        for (int j = 0; j < 16; ++j) cur[j] = Xr[lane + j * 64];
        float acc = 0.f;
#pragma unroll
        for (int j = 0; j < 16; ++j) {
            float4 x = cur[j];
            float4 vv = vsh[lane + j * 64];
            acc += x.x * vv.x + x.y * vv.y + x.z * vv.z + x.w * vv.w;
        }
        acc = wave_sum(acc) * inv;
        sig += acc * acc;
        nfloat4* Or = out4 + (size_t)(r0 + i) * H4;
#pragma unroll
        for (int j = 0; j < 16; ++j) {
            float4 x = cur[j];
            nfloat4 o;
            o.x = fminf(fmaxf(rintf(x.x / scale0), -8.f), 7.f) * scale0;
            o.y = fminf(fmaxf(rintf(x.y / scale0), -8.f), 7.f) * scale0;
            o.z = fminf(fmaxf(rintf(x.z / scale0), -8.f), 7.f) * scale0;
            o.w = fminf(fmaxf(rintf(x.w / scale0), -8.f), 7.f) * scale0;
            __builtin_nontemporal_store(o, &Or[lane + j * 64]);
        }
    }
    if (lane == 0) smn[8 + wid] = sig;
    __syncthreads();
    if (t == 0) atomicAdd(&scal[8], smn[8] + smn[9] + smn[10] + smn[11]);
}

// flag==1 only: compute max|X_adapt| -> scal[11]. Early-exits otherwise.
__global__ __launch_bounds__(256) void fixup_max_kernel(
    const float4* __restrict__ X4, const float4* __restrict__ la4,
    const float4* __restrict__ lb4, float* __restrict__ scal) {
    if (!(scal[8] / (scal[9] + EPSV) > 0.35f)) return;
    __shared__ float sm[4];
    const int t = threadIdx.x;
    const int lane = t & 63;
    const int wid = t >> 6;
    float ma = 0.f;
    const size_t total4 = (size_t)NR * HC / 4;
    for (size_t i = (size_t)blockIdx.x * blockDim.x + t; i < total4;
         i += (size_t)gridDim.x * blockDim.x) {
        float4 x = X4[i];
        int h = (int)(i & (H4 - 1));
        float4 A = la4[h];
        float4 B = lb4[h];
        float ax = x.x + (x.x * (A.x * B.x)) * 0.5f;
        float ay = x.y + (x.y * (A.y * B.y)) * 0.5f;
        float az = x.z + (x.z * (A.z * B.z)) * 0.5f;
        float aw = x.w + (x.w * (A.w * B.w)) * 0.5f;
        ma = fmaxf(ma, fmaxf(fmaxf(fabsf(ax), fabsf(ay)),
                             fmaxf(fabsf(az), fabsf(aw))));
    }
#pragma unroll
    for (int m = 32; m; m >>= 1) ma = fmaxf(ma, __shfl_xor(ma, m));
    if (lane == 0) sm[wid] = ma;
    __syncthreads();
    if (t == 0)
        atomicMax(reinterpret_cast<unsigned*>(&scal[11]),
                  __float_as_uint(fmaxf(fmaxf(sm[0], sm[1]), fmaxf(sm[2], sm[3]))));
}

// flag==1 only: re-quant with adapted values (exact flag-1 branch). Early-exits otherwise.
__global__ __launch_bounds__(256) void fixup_quant_kernel(
    const float4* __restrict__ X4, const float4* __restrict__ la4,
    const float4* __restrict__ lb4, const float* __restrict__ scal,
    float4* __restrict__ out4) {
    if (!(scal[8] / (scal[9] + EPSV) > 0.35f)) return;
    const float mv = __uint_as_float(reinterpret_cast<const unsigned*>(scal)[11]);
    const float scale = (mv < EPSV) ? 1.0f : mv / 7.0f;
    const size_t total4 = (size_t)NR * HC / 4;
    for (size_t i = (size_t)blockIdx.x * blockDim.x + threadIdx.x; i < total4;
         i += (size_t)gridDim.x * blockDim.x) {
        float4 x = X4[i];
        int h = (int)(i & (H4 - 1));
        float4 A = la4[h];
        float4 B = lb4[h];
        x.x += (x.x * (A.x * B.x)) * 0.5f;
        x.y += (x.y * (A.y * B.y)) * 0.5f;
        x.z += (x.z * (A.z * B.z)) * 0.5f;
        x.w += (x.w * (A.w * B.w)) * 0.5f;
        float4 o;
        o.x = fminf(fmaxf(rintf(x.x / scale), -8.f), 7.f) * scale;
        o.y = fminf(fmaxf(rintf(x.y / scale), -8.f), 7.f) * scale;
        o.z = fminf(fmaxf(rintf(x.z / scale), -8.f), 7.f) * scale;
        o.w = fminf(fmaxf(rintf(x.w / scale), -8.f), 7.f) * scale;
        out4[i] = o;
    }
}

extern "C" void kernel_launch(void* const* d_in, const int* in_sizes, int n_in,
                              void* d_out, int out_size, void* d_ws, size_t ws_size,
                              hipStream_t stream) {
    const float4* X4 = reinterpret_cast<const float4*>(d_in[0]);
    const float4* la4 = reinterpret_cast<const float4*>(d_in[1]);
    const float4* lb4 = reinterpret_cast<const float4*>(d_in[2]);
    const float4* v04 = reinterpret_cast<const float4*>(d_in[3]);
    float* ws = (float*)d_ws;
    float* w1 = ws;
    float* w2 = ws + HC;
    float* scal = ws + 2 * HC;
    float4* part4 = reinterpret_cast<float4*>(d_out);
    const float* part = (const float*)d_out;

    // zero w1 + w2 + scal in one memset
    (void)hipMemsetAsync(ws, 0, (2 * HC + 16) * sizeof(float), stream);

    // power iteration 1: w1 = X^T X v0   (+ frob, max|X|)
    xtxv_kernel<0, 1><<<NB, 256, 0, stream>>>(X4, v04, part4, scal);
    reduce_part_kernel<<<NB, 256, 0, stream>>>(part, w1);

    // power iteration 2: w2 = X^T X (w1/||w1||)
    xtxv_kernel<1, 0><<<NB, 256, 0, stream>>>(X4, reinterpret_cast<const float4*>(w1),
                                              part4, scal);
    reduce_part_kernel<<<NB, 256, 0, stream>>>(part, w2);

    // sigma^2 + optimistic quant in one pass (nt stores; overwrites partial scratch)
    quantsig_kernel<<<NB, 256, 0, stream>>>(X4, reinterpret_cast<const float4*>(w2),
                                            scal, reinterpret_cast<nfloat4*>(d_out));

    // rare flag==1 path (both early-exit on flag==0)
    fixup_max_kernel<<<1024, 256, 0, stream>>>(X4, la4, lb4, scal);
    fixup_quant_kernel<<<1024, 256, 0, stream>>>(X4, la4, lb4, scal,
                                                 reinterpret_cast<float4*>(d_out));
}